// Round 5
// baseline (7137.143 us; speedup 1.0000x reference)
//
#include <hip/hip_runtime.h>
#include <stdint.h>

// LSTM encoder: B=64, S=512, V=32000, E=512, H=1024. Returns final (h, c) fp32.
//
// Round-14: fused detect+fetch via acquire-fence + cached sweep, with
// streaming MFMAs. r9 (flags) and r13 (sentinel) both floor at ~4.9us/step
// because detect and fetch are two serialized MALL RTs, and per-wave agent
// polls can't dedup in L2. Fix:
//  - Poll round = __builtin_amdgcn_fence(ACQUIRE,"agent") + CACHED loads of
//    still-invalid units. The fence invalidates stale L2 lines (that is
//    acquire's architectural job at device scope); the refill populates the
//    XCD's L2 so all 32 blocks/XCD share ONE MALL fetch per line per round.
//    The polled bytes ARE the operand: detect==fetch, one RT.
//  - Streaming compute: each kc unit's MFMA issues in the round where it
//    validates (wave-uniform __all per kc); the last unit leaves only its
//    own MFMA chain on the critical path.
//  - Registers survive fences: eA emb prefetch (regs), Wl (LDS), creg all
//    unaffected by L2 invalidation.
//  - Safety valve: rounds >=12 switch to r13-proven agent-scope reloads
//    (guaranteed-fresh) -- converges even if the fence under-invalidates
//    on gfx950. No unbounded novel spin.
//  - Ground truth unchanged (r11-r13-proven): LSB-odd validity, per-run
//    init clear of h regions, fire-and-forget 8B agent h-stores,
//    per-wave self-pacing, no flags/barriers/clock.

#define Bsz 64
#define Ssz 512
#define Esz 512
#define Hsz 1024
#define G4  4096
#define Ksz 1536
#define KC  48      // Ksz/32
#define NBLK 256
#define AUNITS 12288            // 16B units per A buffer (KC*256)

typedef float f32x4 __attribute__((ext_vector_type(4)));
typedef short bf16x8 __attribute__((ext_vector_type(8)));
typedef unsigned long long u64;

// A unit(row,kc,q) = kc*256 + (row>>4)*64 + q*16 + (row&15)
// Wf unit(blk,kc,q,r) = (blk*48+kc)*64 + q*16 + r, r = gate*4+j  (n-col)

__device__ __forceinline__ unsigned short f2bf(float f) {
  union { float f; uint32_t u; } v; v.f = f;
  return (unsigned short)((v.u + 0x7FFFu + ((v.u >> 16) & 1u)) >> 16);  // RNE
}
// nearest ODD-LSB bf16 (validity bit). trunc|1 IS the nearest odd value.
__device__ __forceinline__ unsigned short f2bf_odd(float f) {
  union { float f; uint32_t u; } v; v.f = f;
  return (unsigned short)((v.u >> 16) | 1u);
}
__device__ __forceinline__ float fsig(float x) {
  return __builtin_amdgcn_rcpf(1.0f + __expf(-x));
}
__device__ __forceinline__ float ftanh(float x) {
  return 2.0f * fsig(2.0f * x) - 1.0f;
}

__global__ __launch_bounds__(1024) void wf_kernel(
    const float* __restrict__ Wih, const float* __restrict__ Whh,
    unsigned short* __restrict__ Wf)
{
  __shared__ float tile[32][33];
  const int j0 = blockIdx.x * 32;           // gate-col tile
  const int k0 = blockIdx.y * 32;           // k tile
  const int tx = threadIdx.x & 31, ty = threadIdx.x >> 5;
  const int k = k0 + ty;
  tile[ty][tx] = (k < Hsz) ? Whh[(size_t)k * G4 + (j0 + tx)]
                           : Wih[(size_t)(k - Hsz) * G4 + (j0 + tx)];
  __syncthreads();
  if (threadIdx.x < 128) {
    const int gl = threadIdx.x & 31;        // local gate col in tile
    const int q8 = threadIdx.x >> 5;        // k-octet within kc
    const int g  = j0 + gl;                 // global gate col
    const int blk  = (g & 1023) >> 2;
    const int gate = g >> 10;
    const int r    = gate * 4 + (g & 3);    // n-col within block tile
    const int kc   = k0 >> 5;
    unsigned short pack[8];
    #pragma unroll
    for (int jj = 0; jj < 8; ++jj) pack[jj] = f2bf(tile[q8 * 8 + jj][gl]);
    const size_t unit = (size_t)((blk * KC + kc) * 64 + q8 * 16 + r);
    *(bf16x8*)(Wf + unit * 8) = *(bf16x8*)pack;
  }
}

// Per A[t]: clear h region to even/invalid (t=0: odd-LSB "zero" h) and
// write the emb region. Clearing every run kills cross-run stale-valid data.
__global__ __launch_bounds__(256) void init_kernel(
    const int* __restrict__ seq, const float* __restrict__ emb,
    unsigned short* __restrict__ Abufs, int* __restrict__ bar)
{
  const int t = blockIdx.x, tid = threadIdx.x;
  unsigned short* At = Abufs + (size_t)t * AUNITS * 8;
  {  // h region = units [0, 8192) = kc 0..31
    uint4 z;
    const uint32_t zv = (t == 0) ? 0x00010001u : 0u;
    z.x = z.y = z.z = z.w = zv;
    for (int i = tid; i < 8192; i += 256) ((uint4*)At)[i] = z;
  }
  const int c = 2 * tid;                    // emb col pair
  const int kc = 32 + (c >> 5), q = (c >> 3) & 3, j = c & 7;
  for (int row = 0; row < Bsz; ++row) {
    const int token = seq[row * Ssz + t];
    float2 e = ((const float2*)(emb + (size_t)token * Esz))[tid];
    uint32_t pe = (uint32_t)f2bf(e.x) | ((uint32_t)f2bf(e.y) << 16);
    const size_t unit = (size_t)(kc * 256 + (row >> 4) * 64 + q * 16 + (row & 15));
    *(uint32_t*)(At + unit * 8 + j) = pe;
  }
  if (t == 0) {
    for (int i = tid; i < 1024; i += 256) bar[i] = 0;
  }
}

__global__ __launch_bounds__(256, 1) void lstm_kernel(
    const float* __restrict__ bias, const unsigned short* __restrict__ Wf,
    unsigned short* __restrict__ Abufs,
    int* __restrict__ bar, float* __restrict__ out)
{
  (void)bar;
  const int blk  = blockIdx.x;          // owns h-cols [blk*4, blk*4+4)
  const int tid  = threadIdx.x;
  const int lane = tid & 63;
  const int w    = tid >> 6;            // wave = M-tile rows [w*16, w*16+16)
  const int l15  = lane & 15, quad = lane >> 4;

  __shared__ uint4 Wl[KC * 64];                 // 48 KB, resident all steps
  __shared__ unsigned short Hs[4][16][4];       // 512 B per-wave h transpose

  {  // one-time: W slice -> LDS
    const uint4* wfb = (const uint4*)Wf + (size_t)blk * (KC * 64);
    for (int i = tid; i < KC * 64; i += 256) Wl[i] = wfb[i];
  }

  // cell ownership: lanes l15<4 own (rows w*16+quad*4+r, col blk*4+l15)
  const bool owner = (l15 < 4);
  const int  bj = blk * 4 + (l15 & 3);
  const float bi  = bias[bj],        bf_ = bias[Hsz + bj];
  const float bg_ = bias[2*Hsz + bj], bo  = bias[3*Hsz + bj];
  float creg[4] = {0.f, 0.f, 0.f, 0.f};

  // h-store addressing: this block's cols live at (hkc, hq, hj0)
  const int hkc = blk >> 3, hq = (blk >> 1) & 3, hj0 = (blk & 1) * 4;

  __syncthreads();                      // Wl staged (only block barrier)

  // ---- emb prefetch (1 step ahead) ----
  uint4 eA[16];
  {
    const uint4* E0 = (const uint4*)Abufs;
    #pragma unroll
    for (int i = 0; i < 16; ++i) eA[i] = E0[(32 + i) * 256 + w * 64 + lane];
  }

  const u64 M = 0x0001000100010001ull;

  for (int t = 0; t < Ssz; ++t) {
    // ---- emb MFMAs (register-only), shadow during producers' store flight
    f32x4 accE = {0.f, 0.f, 0.f, 0.f};
    #pragma unroll
    for (int i = 0; i < 16; ++i)
      accE = __builtin_amdgcn_mfma_f32_16x16x32_bf16(
          __builtin_bit_cast(bf16x8, eA[i]),
          __builtin_bit_cast(bf16x8, Wl[(32 + i) * 64 + lane]), accE, 0, 0, 0);

    asm volatile("" ::: "memory");

    // ---- fused detect+fetch poll with streaming MFMAs ----
    const uint4* Ac = (const uint4*)(Abufs + (size_t)t * AUNITS * 8);
    uint4 abuf[32];
    f32x4 acc0 = {0.f, 0.f, 0.f, 0.f};
    f32x4 acc1 = {0.f, 0.f, 0.f, 0.f};
    f32x4 acc2 = {0.f, 0.f, 0.f, 0.f};
    f32x4 acc3 = {0.f, 0.f, 0.f, 0.f};
    uint32_t bad = 0xFFFFFFFFu;         // wave-uniform: units not yet MFMA'd
    int round = 0;
    for (;;) {
      if (__builtin_expect(round < 12, 1)) {
        // acquire fence: invalidate stale L2 lines; cached refill is
        // L2-deduped across the XCD's 32 blocks.
        __builtin_amdgcn_fence(__ATOMIC_ACQUIRE, "agent");
        #pragma unroll
        for (int kc = 0; kc < 32; ++kc)
          if (bad & (1u << kc)) abuf[kc] = Ac[kc * 256 + w * 64 + lane];
      } else {
        // safety valve: agent-scope (coherence-point) reloads, proven fresh
        #pragma unroll
        for (int kc = 0; kc < 32; ++kc)
          if (bad & (1u << kc)) {
            const u64* base = (const u64*)Ac + (size_t)(kc * 256 + w * 64 + lane) * 2;
            u64 lo = __hip_atomic_load(base,     __ATOMIC_RELAXED, __HIP_MEMORY_SCOPE_AGENT);
            u64 hi = __hip_atomic_load(base + 1, __ATOMIC_RELAXED, __HIP_MEMORY_SCOPE_AGENT);
            abuf[kc].x = (uint32_t)lo; abuf[kc].y = (uint32_t)(lo >> 32);
            abuf[kc].z = (uint32_t)hi; abuf[kc].w = (uint32_t)(hi >> 32);
          }
      }
      __builtin_amdgcn_sched_barrier(0);

      uint32_t got = 0;
      #pragma unroll
      for (int kc = 0; kc < 32; ++kc)
        if (bad & (1u << kc)) {
          u64 lo = ((u64)abuf[kc].y << 32) | abuf[kc].x;
          u64 hi = ((u64)abuf[kc].w << 32) | abuf[kc].z;
          const bool ok = (((lo & M) == M) && ((hi & M) == M));
          if (__all(ok)) got |= (1u << kc);
        }

      // stream MFMAs for units validated this round
      #pragma unroll
      for (int kc = 0; kc < 32; ++kc)
        if (got & (1u << kc)) {
          const bf16x8 av = __builtin_bit_cast(bf16x8, abuf[kc]);
          const bf16x8 bv = __builtin_bit_cast(bf16x8, Wl[kc * 64 + lane]);
          if      ((kc & 3) == 0) acc0 = __builtin_amdgcn_mfma_f32_16x16x32_bf16(av, bv, acc0, 0, 0, 0);
          else if ((kc & 3) == 1) acc1 = __builtin_amdgcn_mfma_f32_16x16x32_bf16(av, bv, acc1, 0, 0, 0);
          else if ((kc & 3) == 2) acc2 = __builtin_amdgcn_mfma_f32_16x16x32_bf16(av, bv, acc2, 0, 0, 0);
          else                    acc3 = __builtin_amdgcn_mfma_f32_16x16x32_bf16(av, bv, acc3, 0, 0, 0);
        }

      bad &= ~got;
      if (!bad) break;
      ++round;
      if (round > 2) __builtin_amdgcn_s_sleep(1);
    }

    f32x4 acc;
    acc.x = accE.x + (acc0.x + acc1.x) + (acc2.x + acc3.x);
    acc.y = accE.y + (acc0.y + acc1.y) + (acc2.y + acc3.y);
    acc.z = accE.z + (acc0.z + acc1.z) + (acc2.z + acc3.z);
    acc.w = accE.w + (acc0.w + acc1.w) + (acc2.w + acc3.w);

    // ---- in-wave LSTM cell (acc[r]: gate l15>>2, col l15&3, row +quad*4+r)
    float hv[4];
    #pragma unroll
    for (int r = 0; r < 4; ++r) {
      float gf = __shfl_xor(acc[r], 4);
      float gg = __shfl_xor(acc[r], 8);
      float go = __shfl_xor(acc[r], 12);
      float c  = fsig(gf + bf_) * creg[r]
               + fsig(acc[r] + bi) * ftanh(gg + bg_);
      float h  = fsig(go + bo) * ftanh(c);
      if (owner) { creg[r] = c; hv[r] = h; }
    }

    if (t == Ssz - 1) {
      if (owner) {
        #pragma unroll
        for (int r = 0; r < 4; ++r) {
          const int row = w * 16 + quad * 4 + r;
          out[(size_t)row * Hsz + bj] = hv[r];
          out[(size_t)(Bsz * Hsz) + (size_t)row * Hsz + bj] = creg[r];
        }
      }
      return;
    }

    // ---- fire-and-forget: per-wave LDS transpose -> 8B odd-LSB u64 store
    if (owner) {
      #pragma unroll
      for (int r = 0; r < 4; ++r) Hs[w][quad * 4 + r][l15] = f2bf_odd(hv[r]);
    }
    unsigned short* An = Abufs + (size_t)(t + 1) * AUNITS * 8;
    if (lane < 16) {
      u64 hp = *(const u64*)&Hs[w][lane][0];
      const size_t unit = (size_t)(hkc * 256 + w * 64 + hq * 16 + lane);
      __hip_atomic_store((u64*)(An + unit * 8 + hj0), hp,
                         __ATOMIC_RELAXED, __HIP_MEMORY_SCOPE_AGENT);
    }
    asm volatile("" ::: "memory");

    // ---- refill emb prefetch for t+1 (regs survive later fences) ----
    const uint4* An4 = (const uint4*)An;
    #pragma unroll
    for (int i = 0; i < 16; ++i) eA[i] = An4[(32 + i) * 256 + w * 64 + lane];
  }
}

extern "C" void kernel_launch(void* const* d_in, const int* in_sizes, int n_in,
                              void* d_out, int out_size, void* d_ws, size_t ws_size,
                              hipStream_t stream) {
  (void)in_sizes; (void)n_in; (void)out_size; (void)ws_size;
  const int*   seq  = (const int*)d_in[0];     // [64][512] int32
  const float* emb  = (const float*)d_in[1];   // [32000][512] fp32
  const float* Wih  = (const float*)d_in[2];   // [512][4096] fp32
  const float* Whh  = (const float*)d_in[3];   // [1024][4096] fp32
  const float* bias = (const float*)d_in[4];   // [4096] fp32
  float* out = (float*)d_out;                  // h[64][1024] then c[64][1024]

  unsigned short* Wf    = (unsigned short*)d_ws;              // 12.58 MB
  unsigned short* Abufs = Wf + (size_t)NBLK * KC * 64 * 8;    // 512*192KB
  int* bar = (int*)(Abufs + (size_t)Ssz * AUNITS * 8);        // unused pad

  wf_kernel<<<dim3(G4 / 32, Ksz / 32), 1024, 0, stream>>>(Wih, Whh, Wf);
  init_kernel<<<Ssz, 256, 0, stream>>>(seq, emb, Abufs, bar);
  lstm_kernel<<<NBLK, 256, 0, stream>>>(bias, Wf, Abufs, bar, out);
}

// Round 6
// 2506.459 us; speedup vs baseline: 2.8475x; 2.8475x over previous
//
#include <hip/hip_runtime.h>
#include <stdint.h>

// LSTM encoder: B=64, S=512, V=32000, E=512, H=1024. Returns final (h, c) fp32.
//
// Round-15: self-calibrating paced sweep (anchored deadline + AIMD gap).
// Evidence: r9 (flags) and r13 (sentinel) both floor at ~4.9us/step = ~3
// serialized MALL RTs (store-flight, detect, fetch). Agent polls can't be
// widened (no L2 dedup: full-width agent poll = 32MB/step = 5us of BW,
// r12's killer). r14's fences caused 1.7GB of L2 writeback traffic -> dead.
// The only ~1-RT structure: PREDICT readiness, then do the single cached
// (XCD-L2-deduped) sweep directly. r11's clock failed on (a) absolute
// schedule that never re-anchors after a miss, (b) serialized recovery.
// r15 fixes both:
//  - Keep r13's proven core: cached 32-unit sweep -> LSB validate ->
//    batched concurrent agent recovery (~1 RT/round regardless of count).
//  - Add pacing: wait until dl, sweep, and re-anchor dl = V + D where V =
//    realtime at validation-complete (a globally-shared event: every block
//    waits on the same last producer). No drift, self-healing skew.
//  - D adapts by AIMD (clean: -2; any recovery: +12; bounds [40,1500]) --
//    REFCLK-rate-agnostic (D is learned in native ticks), converges to the
//    true cell+store+flight gap, hovers at ~85% clean rate.
//  - Clean step cost: ONE cached dedup'd sweep, zero detect RTs.
//  - Worst case (clock useless): recovery-paced ~= r13. All waits bounded
//    (monotone clock; recovery is r13-proven convergent, producers are
//    fire-and-forget BEFORE any wait).
//  - Ground truth unchanged (r11-r14-proven): LSB-odd validity, per-run
//    init clear of h regions, agent 8B h-stores, no flags/barriers/fences.

#define Bsz 64
#define Ssz 512
#define Esz 512
#define Hsz 1024
#define G4  4096
#define Ksz 1536
#define KC  48      // Ksz/32
#define NBLK 256
#define AUNITS 12288            // 16B units per A buffer (KC*256)

#define D_INIT 400u
#define D_MIN  40u
#define D_MAX  1500u

typedef float f32x4 __attribute__((ext_vector_type(4)));
typedef short bf16x8 __attribute__((ext_vector_type(8)));
typedef unsigned long long u64;

// A unit(row,kc,q) = kc*256 + (row>>4)*64 + q*16 + (row&15)
// Wf unit(blk,kc,q,r) = (blk*48+kc)*64 + q*16 + r, r = gate*4+j  (n-col)

__device__ __forceinline__ unsigned short f2bf(float f) {
  union { float f; uint32_t u; } v; v.f = f;
  return (unsigned short)((v.u + 0x7FFFu + ((v.u >> 16) & 1u)) >> 16);  // RNE
}
// nearest ODD-LSB bf16 (validity bit). trunc|1 IS the nearest odd value.
__device__ __forceinline__ unsigned short f2bf_odd(float f) {
  union { float f; uint32_t u; } v; v.f = f;
  return (unsigned short)((v.u >> 16) | 1u);
}
__device__ __forceinline__ float fsig(float x) {
  return __builtin_amdgcn_rcpf(1.0f + __expf(-x));
}
__device__ __forceinline__ float ftanh(float x) {
  return 2.0f * fsig(2.0f * x) - 1.0f;
}

__global__ __launch_bounds__(1024) void wf_kernel(
    const float* __restrict__ Wih, const float* __restrict__ Whh,
    unsigned short* __restrict__ Wf)
{
  __shared__ float tile[32][33];
  const int j0 = blockIdx.x * 32;           // gate-col tile
  const int k0 = blockIdx.y * 32;           // k tile
  const int tx = threadIdx.x & 31, ty = threadIdx.x >> 5;
  const int k = k0 + ty;
  tile[ty][tx] = (k < Hsz) ? Whh[(size_t)k * G4 + (j0 + tx)]
                           : Wih[(size_t)(k - Hsz) * G4 + (j0 + tx)];
  __syncthreads();
  if (threadIdx.x < 128) {
    const int gl = threadIdx.x & 31;        // local gate col in tile
    const int q8 = threadIdx.x >> 5;        // k-octet within kc
    const int g  = j0 + gl;                 // global gate col
    const int blk  = (g & 1023) >> 2;
    const int gate = g >> 10;
    const int r    = gate * 4 + (g & 3);    // n-col within block tile
    const int kc   = k0 >> 5;
    unsigned short pack[8];
    #pragma unroll
    for (int jj = 0; jj < 8; ++jj) pack[jj] = f2bf(tile[q8 * 8 + jj][gl]);
    const size_t unit = (size_t)((blk * KC + kc) * 64 + q8 * 16 + r);
    *(bf16x8*)(Wf + unit * 8) = *(bf16x8*)pack;
  }
}

// Per A[t]: clear h region to even/invalid (t=0: odd-LSB "zero" h) and
// write the emb region. Clearing every run kills cross-run stale-valid data.
__global__ __launch_bounds__(256) void init_kernel(
    const int* __restrict__ seq, const float* __restrict__ emb,
    unsigned short* __restrict__ Abufs, int* __restrict__ bar)
{
  const int t = blockIdx.x, tid = threadIdx.x;
  unsigned short* At = Abufs + (size_t)t * AUNITS * 8;
  {  // h region = units [0, 8192) = kc 0..31
    uint4 z;
    const uint32_t zv = (t == 0) ? 0x00010001u : 0u;
    z.x = z.y = z.z = z.w = zv;
    for (int i = tid; i < 8192; i += 256) ((uint4*)At)[i] = z;
  }
  const int c = 2 * tid;                    // emb col pair
  const int kc = 32 + (c >> 5), q = (c >> 3) & 3, j = c & 7;
  for (int row = 0; row < Bsz; ++row) {
    const int token = seq[row * Ssz + t];
    float2 e = ((const float2*)(emb + (size_t)token * Esz))[tid];
    uint32_t pe = (uint32_t)f2bf(e.x) | ((uint32_t)f2bf(e.y) << 16);
    const size_t unit = (size_t)(kc * 256 + (row >> 4) * 64 + q * 16 + (row & 15));
    *(uint32_t*)(At + unit * 8 + j) = pe;
  }
  if (t == 0) {
    for (int i = tid; i < 1024; i += 256) bar[i] = 0;
  }
}

__global__ __launch_bounds__(256, 1) void lstm_kernel(
    const float* __restrict__ bias, const unsigned short* __restrict__ Wf,
    unsigned short* __restrict__ Abufs,
    int* __restrict__ bar, float* __restrict__ out)
{
  (void)bar;
  const int blk  = blockIdx.x;          // owns h-cols [blk*4, blk*4+4)
  const int tid  = threadIdx.x;
  const int lane = tid & 63;
  const int w    = tid >> 6;            // wave = M-tile rows [w*16, w*16+16)
  const int l15  = lane & 15, quad = lane >> 4;

  __shared__ uint4 Wl[KC * 64];                 // 48 KB, resident all steps
  __shared__ unsigned short Hs[4][16][4];       // 512 B per-wave h transpose

  {  // one-time: W slice -> LDS
    const uint4* wfb = (const uint4*)Wf + (size_t)blk * (KC * 64);
    for (int i = tid; i < KC * 64; i += 256) Wl[i] = wfb[i];
  }

  // cell ownership: lanes l15<4 own (rows w*16+quad*4+r, col blk*4+l15)
  const bool owner = (l15 < 4);
  const int  bj = blk * 4 + (l15 & 3);
  const float bi  = bias[bj],        bf_ = bias[Hsz + bj];
  const float bg_ = bias[2*Hsz + bj], bo  = bias[3*Hsz + bj];
  float creg[4] = {0.f, 0.f, 0.f, 0.f};

  // h-store addressing: this block's cols live at (hkc, hq, hj0)
  const int hkc = blk >> 3, hq = (blk >> 1) & 3, hj0 = (blk & 1) * 4;

  __syncthreads();                      // Wl staged (only block barrier)

  // ---- emb prefetch (1 step ahead) ----
  uint4 eA[16];
  {
    const uint4* E0 = (const uint4*)Abufs;
    #pragma unroll
    for (int i = 0; i < 16; ++i) eA[i] = E0[(32 + i) * 256 + w * 64 + lane];
  }

  const u64 M = 0x0001000100010001ull;

  u64 dl = 0;                 // deadline for next sweep (anchored at V + D)
  uint32_t D = D_INIT;        // AIMD gap, native REFCLK ticks

  for (int t = 0; t < Ssz; ++t) {
    // ---- emb MFMAs (register-only), shadow work ----
    f32x4 accE = {0.f, 0.f, 0.f, 0.f};
    #pragma unroll
    for (int i = 0; i < 16; ++i)
      accE = __builtin_amdgcn_mfma_f32_16x16x32_bf16(
          __builtin_bit_cast(bf16x8, eA[i]),
          __builtin_bit_cast(bf16x8, Wl[(32 + i) * 64 + lane]), accE, 0, 0, 0);

    // ---- pacing: wait for anchored deadline (terminates: clock monotone)
    while (__builtin_amdgcn_s_memrealtime() < dl) __builtin_amdgcn_s_sleep(1);
    asm volatile("" ::: "memory");

    // ---- single cached sweep kc=0..31 (XCD-L2 dedup across blocks) ----
    const uint4* Ac = (const uint4*)(Abufs + (size_t)t * AUNITS * 8);
    uint4 abuf[32];
    #pragma unroll
    for (int kc = 0; kc < 32; ++kc) abuf[kc] = Ac[kc * 256 + w * 64 + lane];

    __builtin_amdgcn_sched_barrier(0);

    uint32_t bad = 0;
    #pragma unroll
    for (int kc = 0; kc < 32; ++kc) {
      u64 lo = ((u64)abuf[kc].y << 32) | abuf[kc].x;
      u64 hi = ((u64)abuf[kc].w << 32) | abuf[kc].z;
      if (((lo & M) != M) || ((hi & M) != M)) bad |= (1u << kc);
    }
    const bool missed = __any((int)(bad != 0u));

    // ---- batched recovery: issue-pass (concurrent agent reloads of bad
    //      units only) then check-pass; ~1 RT per round ----
    int rnd = 0;
    while (__any((int)(bad != 0u))) {
      if (rnd > 0) __builtin_amdgcn_s_sleep(2);
      ++rnd;
      #pragma unroll
      for (int kc = 0; kc < 32; ++kc) {
        if (bad & (1u << kc)) {
          const u64* base = (const u64*)Ac + (size_t)(kc * 256 + w * 64 + lane) * 2;
          u64 lo = __hip_atomic_load(base,     __ATOMIC_RELAXED, __HIP_MEMORY_SCOPE_AGENT);
          u64 hi = __hip_atomic_load(base + 1, __ATOMIC_RELAXED, __HIP_MEMORY_SCOPE_AGENT);
          abuf[kc].x = (uint32_t)lo; abuf[kc].y = (uint32_t)(lo >> 32);
          abuf[kc].z = (uint32_t)hi; abuf[kc].w = (uint32_t)(hi >> 32);
        }
      }
      __builtin_amdgcn_sched_barrier(0);
      uint32_t nbad = 0;
      #pragma unroll
      for (int kc = 0; kc < 32; ++kc) {
        if (bad & (1u << kc)) {
          u64 lo = ((u64)abuf[kc].y << 32) | abuf[kc].x;
          u64 hi = ((u64)abuf[kc].w << 32) | abuf[kc].z;
          if (((lo & M) != M) || ((hi & M) != M)) nbad |= (1u << kc);
        }
      }
      bad = nbad;
    }

    // ---- anchor + AIMD: V (validation-complete) is a shared event ----
    {
      const u64 V = __builtin_amdgcn_s_memrealtime();
      if (missed) { D = (D + 12u > D_MAX) ? D_MAX : D + 12u; }
      else        { D = (D > D_MIN + 2u) ? D - 2u : D_MIN; }
      dl = V + (u64)D;
    }

    // ---- h-GEMM: 32 MFMAs, 4 accumulation chains ----
    f32x4 acc0 = {0.f, 0.f, 0.f, 0.f};
    f32x4 acc1 = {0.f, 0.f, 0.f, 0.f};
    f32x4 acc2 = {0.f, 0.f, 0.f, 0.f};
    f32x4 acc3 = {0.f, 0.f, 0.f, 0.f};
    #pragma unroll
    for (int kc = 0; kc < 32; ++kc) {
      const bf16x8 av = __builtin_bit_cast(bf16x8, abuf[kc]);
      const bf16x8 bv = __builtin_bit_cast(bf16x8, Wl[kc * 64 + lane]);
      if      ((kc & 3) == 0) acc0 = __builtin_amdgcn_mfma_f32_16x16x32_bf16(av, bv, acc0, 0, 0, 0);
      else if ((kc & 3) == 1) acc1 = __builtin_amdgcn_mfma_f32_16x16x32_bf16(av, bv, acc1, 0, 0, 0);
      else if ((kc & 3) == 2) acc2 = __builtin_amdgcn_mfma_f32_16x16x32_bf16(av, bv, acc2, 0, 0, 0);
      else                    acc3 = __builtin_amdgcn_mfma_f32_16x16x32_bf16(av, bv, acc3, 0, 0, 0);
    }
    f32x4 acc;
    acc.x = accE.x + (acc0.x + acc1.x) + (acc2.x + acc3.x);
    acc.y = accE.y + (acc0.y + acc1.y) + (acc2.y + acc3.y);
    acc.z = accE.z + (acc0.z + acc1.z) + (acc2.z + acc3.z);
    acc.w = accE.w + (acc0.w + acc1.w) + (acc2.w + acc3.w);

    // ---- in-wave LSTM cell (acc[r]: gate l15>>2, col l15&3, row +quad*4+r)
    float hv[4];
    #pragma unroll
    for (int r = 0; r < 4; ++r) {
      float gf = __shfl_xor(acc[r], 4);
      float gg = __shfl_xor(acc[r], 8);
      float go = __shfl_xor(acc[r], 12);
      float c  = fsig(gf + bf_) * creg[r]
               + fsig(acc[r] + bi) * ftanh(gg + bg_);
      float h  = fsig(go + bo) * ftanh(c);
      if (owner) { creg[r] = c; hv[r] = h; }
    }

    if (t == Ssz - 1) {
      if (owner) {
        #pragma unroll
        for (int r = 0; r < 4; ++r) {
          const int row = w * 16 + quad * 4 + r;
          out[(size_t)row * Hsz + bj] = hv[r];
          out[(size_t)(Bsz * Hsz) + (size_t)row * Hsz + bj] = creg[r];
        }
      }
      return;
    }

    // ---- fire-and-forget: per-wave LDS transpose -> 8B odd-LSB u64 store
    if (owner) {
      #pragma unroll
      for (int r = 0; r < 4; ++r) Hs[w][quad * 4 + r][l15] = f2bf_odd(hv[r]);
    }
    unsigned short* An = Abufs + (size_t)(t + 1) * AUNITS * 8;
    if (lane < 16) {
      u64 hp = *(const u64*)&Hs[w][lane][0];
      const size_t unit = (size_t)(hkc * 256 + w * 64 + hq * 16 + lane);
      __hip_atomic_store((u64*)(An + unit * 8 + hj0), hp,
                         __ATOMIC_RELAXED, __HIP_MEMORY_SCOPE_AGENT);
    }
    asm volatile("" ::: "memory");

    // ---- refill emb prefetch for t+1 (init-written, always valid) ----
    const uint4* An4 = (const uint4*)An;
    #pragma unroll
    for (int i = 0; i < 16; ++i) eA[i] = An4[(32 + i) * 256 + w * 64 + lane];
  }
}

extern "C" void kernel_launch(void* const* d_in, const int* in_sizes, int n_in,
                              void* d_out, int out_size, void* d_ws, size_t ws_size,
                              hipStream_t stream) {
  (void)in_sizes; (void)n_in; (void)out_size; (void)ws_size;
  const int*   seq  = (const int*)d_in[0];     // [64][512] int32
  const float* emb  = (const float*)d_in[1];   // [32000][512] fp32
  const float* Wih  = (const float*)d_in[2];   // [512][4096] fp32
  const float* Whh  = (const float*)d_in[3];   // [1024][4096] fp32
  const float* bias = (const float*)d_in[4];   // [4096] fp32
  float* out = (float*)d_out;                  // h[64][1024] then c[64][1024]

  unsigned short* Wf    = (unsigned short*)d_ws;              // 12.58 MB
  unsigned short* Abufs = Wf + (size_t)NBLK * KC * 64 * 8;    // 512*192KB
  int* bar = (int*)(Abufs + (size_t)Ssz * AUNITS * 8);        // unused pad

  wf_kernel<<<dim3(G4 / 32, Ksz / 32), 1024, 0, stream>>>(Wih, Whh, Wf);
  init_kernel<<<Ssz, 256, 0, stream>>>(seq, emb, Abufs, bar);
  lstm_kernel<<<NBLK, 256, 0, stream>>>(bias, Wf, Abufs, bar, out);
}